// Round 2
// baseline (393.256 us; speedup 1.0000x reference)
//
#include <hip/hip_runtime.h>
#include <stdint.h>

#define NB 32
#define N 512
#define MAXD 10
#define NW 8  // u64 words per 512-bit row

// ---------------- K1: binarize + symmetrize + mask -> packed bitset ----------------
// grid: (36 tile-pairs, B), block 256. Tiles 64x64; __ballot builds one u64 word per row.
// NOTE: node_mask arrives as int32 (harness converts jnp bool -> int).
__global__ __launch_bounds__(256) void k1_pack(const float* __restrict__ adj,
                                               const int* __restrict__ mask,
                                               unsigned long long* __restrict__ gsym) {
    __shared__ float ldsA[64 * 65];  // +1 pad: row & column reads both 2-way (free)
    __shared__ float ldsB[64 * 65];
    __shared__ unsigned char mI[64], mJ[64];
    int p = blockIdx.x;
    int b = blockIdx.y;
    int ti = 0;
    while (p >= 8 - ti) { p -= 8 - ti; ++ti; }
    int tj = ti + p;
    int i0 = ti * 64, j0 = tj * 64;
    int t = threadIdx.x;
    if (t < 64) mI[t] = (mask[b * N + i0 + t] != 0);
    else if (t < 128) mJ[t - 64] = (mask[b * N + j0 + (t - 64)] != 0);
    const float* Ab = adj + (size_t)b * N * N;
    #pragma unroll
    for (int s = 0; s < 4; ++s) {
        int idx = t + 256 * s;          // 0..1023 float4 slots
        int r = idx >> 4, c4 = idx & 15;
        float4 va = *(const float4*)&Ab[(size_t)(i0 + r) * N + j0 + c4 * 4];
        float4 vb = *(const float4*)&Ab[(size_t)(j0 + r) * N + i0 + c4 * 4];
        int o = r * 65 + c4 * 4;
        ldsA[o] = va.x; ldsA[o + 1] = va.y; ldsA[o + 2] = va.z; ldsA[o + 3] = va.w;
        ldsB[o] = vb.x; ldsB[o + 1] = vb.y; ldsB[o + 2] = vb.z; ldsB[o + 3] = vb.w;
    }
    __syncthreads();
    int wave = t >> 6, lane = t & 63;
    // rows of tile ti, word tj
    for (int s = 0; s < 16; ++s) {
        int r = wave * 16 + s;
        bool bit = ((ldsA[r * 65 + lane] > 0.5f) || (ldsB[lane * 65 + r] > 0.5f))
                   && mI[r] && mJ[lane];
        unsigned long long word = __ballot(bit);
        if (lane == 0) gsym[((size_t)b * N + i0 + r) * NW + tj] = word;
    }
    // rows of tile tj, word ti (same value on diagonal tiles -> benign double write)
    for (int s = 0; s < 16; ++s) {
        int r = wave * 16 + s;
        bool bit = ((ldsB[r * 65 + lane] > 0.5f) || (ldsA[lane * 65 + r] > 0.5f))
                   && mJ[r] && mI[lane];
        unsigned long long word = __ballot(bit);
        if (lane == 0) gsym[((size_t)b * N + j0 + r) * NW + ti] = word;
    }
}

// ---------------- K2: bitset BFS, one thread per source row ----------------
// grid: B*8 blocks, 64 threads. LDS: adjacency bitset 32KB (plane-major) + dist bytes 32KB.
__global__ __launch_bounds__(64) void k2_bfs(const unsigned long long* __restrict__ gsym,
                                             const int* __restrict__ mask,
                                             unsigned char* __restrict__ distg) {
    __shared__ unsigned long long adjT[NW * N];   // [w][j] plane-major: 4-way aliasing only
    __shared__ unsigned char distB[64 * N];       // [local_row][j]
    int blk = blockIdx.x;
    int b = blk >> 3;
    int r0 = (blk & 7) * 64;
    int t = threadIdx.x;
    const unsigned long long* gs = gsym + (size_t)b * N * NW;
    for (int q = t; q < N * NW; q += 64) {
        unsigned long long w = gs[q];             // coalesced
        adjT[(q & 7) * N + (q >> 3)] = w;         // transpose to plane-major
    }
    unsigned long long* d64 = (unsigned long long*)distB;
    for (int q = t; q < 64 * N / 8; q += 64)
        d64[q] = 0x0B0B0B0B0B0B0B0BULL;           // UNREACH = 11
    __syncthreads();

    int i = r0 + t;
    bool mi = mask[b * N + i] != 0;
    if (mi) {
        distB[t * N + i] = 0;
        unsigned long long reach[NW] = {};
        unsigned long long frontier[NW] = {};
        reach[i >> 6] = 1ULL << (i & 63);
        frontier[i >> 6] = reach[i >> 6];
        for (int k = 1; k <= MAXD; ++k) {
            unsigned long long acc[NW] = {};
            bool sat = false;
            for (int w = 0; w < NW && !sat; ++w) {
                unsigned long long f = frontier[w];
                while (f) {
                    int j = (w << 6) + __builtin_ctzll(f);
                    f &= f - 1;
                    #pragma unroll
                    for (int e = 0; e < NW; ++e) acc[e] |= adjT[e * N + j];
                    unsigned long long all = acc[0];
                    #pragma unroll
                    for (int e = 1; e < NW; ++e) all &= acc[e];
                    if (all == ~0ULL) { sat = true; break; }  // union saturated: exact
                }
            }
            bool any = false;
            #pragma unroll
            for (int w = 0; w < NW; ++w) {
                unsigned long long nf = acc[w] & ~reach[w];
                frontier[w] = nf;
                reach[w] |= nf;
                if (nf) any = true;
                while (nf) {
                    int j = (w << 6) + __builtin_ctzll(nf);
                    nf &= nf - 1;
                    distB[t * N + j] = (unsigned char)k;
                }
            }
            if (!any) break;
        }
    }
    __syncthreads();
    unsigned long long* dg = (unsigned long long*)distg + (size_t)blk * 64 * (N / 8);
    for (int q = t; q < 64 * (N / 8); q += 64)
        dg[q] = d64[q];                           // coalesced u64 copy-out
}

// ---------------- K3: dist -> emb[dist], the 268 MB streaming write ----------------
// grid: B*N blocks (one per output row), 256 threads, 4 coalesced float4 stores each.
__global__ __launch_bounds__(256) void k3_expand(const unsigned char* __restrict__ distg,
                                                 const float* __restrict__ emb,
                                                 float4* __restrict__ out4) {
    __shared__ unsigned char drow[N];
    __shared__ float4 e4[(MAXD + 2) * 2];
    int row = blockIdx.x;
    int t = threadIdx.x;
    if (t < N / 4)
        ((uint32_t*)drow)[t] = ((const uint32_t*)distg)[(size_t)row * (N / 4) + t];
    if (t >= 128 && t < 128 + (MAXD + 2) * 2)
        e4[t - 128] = ((const float4*)emb)[t - 128];
    __syncthreads();
    size_t base = (size_t)row * (N * 2);
    #pragma unroll
    for (int s = 0; s < 4; ++s) {
        int q = t + 256 * s;      // 0..1023 float4 slots in this row
        int j = q >> 1, h = q & 1;
        int d = drow[j];
        out4[base + q] = e4[d * 2 + h];
    }
}

extern "C" void kernel_launch(void* const* d_in, const int* in_sizes, int n_in,
                              void* d_out, int out_size, void* d_ws, size_t ws_size,
                              hipStream_t stream) {
    const float* adj = (const float*)d_in[0];
    const int* mask = (const int*)d_in[1];  // jnp bool -> int32 per harness convention
    const float* emb = (const float*)d_in[2];
    unsigned long long* gsym = (unsigned long long*)d_ws;                     // 1 MB
    unsigned char* distg = (unsigned char*)d_ws + (size_t)NB * N * NW * 8;    // 8 MB
    k1_pack<<<dim3(36, NB), 256, 0, stream>>>(adj, mask, gsym);
    k2_bfs<<<dim3(NB * 8), 64, 0, stream>>>(gsym, mask, distg);
    k3_expand<<<dim3(NB * N), 256, 0, stream>>>(distg, emb, (float4*)d_out);
}

// Round 4
// 363.773 us; speedup vs baseline: 1.0810x; 1.0810x over previous
//
#include <hip/hip_runtime.h>
#include <stdint.h>

typedef unsigned long long u64;
typedef float vf4 __attribute__((ext_vector_type(4)));  // native vector: nontemporal-store OK

#define NB 32
#define N 512
#define MAXD 10
#define NW 8  // u64 words per 512-bit row

// ---------------- K1: binarize + symmetrize + mask -> packed bitset ----------------
// grid: (36 tile-pairs, B), block 256. Tiles 64x64; __ballot builds one u64 word per row.
// NOTE: node_mask arrives as int32 (harness converts jnp bool -> int).
__global__ __launch_bounds__(256) void k1_pack(const float* __restrict__ adj,
                                               const int* __restrict__ mask,
                                               u64* __restrict__ gsym) {
    __shared__ float ldsA[64 * 65];  // +1 pad: row & column reads both conflict-free
    __shared__ float ldsB[64 * 65];
    __shared__ unsigned char mI[64], mJ[64];
    int p = blockIdx.x;
    int b = blockIdx.y;
    int ti = 0;
    while (p >= 8 - ti) { p -= 8 - ti; ++ti; }
    int tj = ti + p;
    int i0 = ti * 64, j0 = tj * 64;
    int t = threadIdx.x;
    if (t < 64) mI[t] = (mask[b * N + i0 + t] != 0);
    else if (t < 128) mJ[t - 64] = (mask[b * N + j0 + (t - 64)] != 0);
    const float* Ab = adj + (size_t)b * N * N;
    #pragma unroll
    for (int s = 0; s < 4; ++s) {
        int idx = t + 256 * s;          // 0..1023 float4 slots
        int r = idx >> 4, c4 = idx & 15;
        float4 va = *(const float4*)&Ab[(size_t)(i0 + r) * N + j0 + c4 * 4];
        float4 vb = *(const float4*)&Ab[(size_t)(j0 + r) * N + i0 + c4 * 4];
        int o = r * 65 + c4 * 4;
        ldsA[o] = va.x; ldsA[o + 1] = va.y; ldsA[o + 2] = va.z; ldsA[o + 3] = va.w;
        ldsB[o] = vb.x; ldsB[o + 1] = vb.y; ldsB[o + 2] = vb.z; ldsB[o + 3] = vb.w;
    }
    __syncthreads();
    int wave = t >> 6, lane = t & 63;
    // rows of tile ti, word tj
    for (int s = 0; s < 16; ++s) {
        int r = wave * 16 + s;
        bool bit = ((ldsA[r * 65 + lane] > 0.5f) || (ldsB[lane * 65 + r] > 0.5f))
                   && mI[r] && mJ[lane];
        u64 word = __ballot(bit);
        if (lane == 0) gsym[((size_t)b * N + i0 + r) * NW + tj] = word;
    }
    // rows of tile tj, word ti (diagonal tiles: benign identical double write)
    for (int s = 0; s < 16; ++s) {
        int r = wave * 16 + s;
        bool bit = ((ldsB[r * 65 + lane] > 0.5f) || (ldsA[lane * 65 + r] > 0.5f))
                   && mJ[r] && mI[lane];
        u64 word = __ballot(bit);
        if (lane == 0) gsym[((size_t)b * N + j0 + r) * NW + ti] = word;
    }
}

// spread 8 bits -> u64 of 8 bytes each 0/1
__device__ __forceinline__ u64 spread8(unsigned b) {
    u64 x = (u64)(b * 0x01010101u);
    x |= x << 32;                       // broadcast byte to all 8 byte lanes
    x &= 0x8040201008040201ULL;         // byte i keeps bit i
    x += 0x7f7f7f7f7f7f7f7fULL;         // bit7 of byte i = (bit i was set); no cross-byte carry
    return (x >> 7) & 0x0101010101010101ULL;
}

// ---------------- K2: bitset BFS, branch-free distance accumulation ----------------
// dist[j] = sum_{k=0..10} [j not in reach_k]  (reach monotone; never-reached -> 11).
// Bit-sliced 4-bit counters over 512-bit rows; no divergent per-bit write loops.
// grid: B*8 blocks, 64 threads (one thread per source row).
__global__ __launch_bounds__(64) void k2_bfs(const u64* __restrict__ gsym,
                                             const int* __restrict__ mask,
                                             u64* __restrict__ distg64) {
    __shared__ u64 adjT[NW * N];      // 32 KB, plane-major [w][j]: 4-way aliasing only
    __shared__ u64 outB[64 * 65];     // packed dist bytes, pad 65 to break stride-128
    int blk = blockIdx.x;
    int b = blk >> 3;
    int r0 = (blk & 7) * 64;
    int t = threadIdx.x;
    const u64* gs = gsym + (size_t)b * N * NW;
    for (int q = t; q < N * NW; q += 64) {
        u64 w = gs[q];                           // coalesced global read
        adjT[(q & 7) * N + (q >> 3)] = w;        // transpose to plane-major
    }
    __syncthreads();

    int i = r0 + t;
    bool mi = mask[b * N + i] != 0;
    u64 c0[NW], c1[NW], c2[NW], c3[NW];
    #pragma unroll
    for (int w = 0; w < NW; ++w) { c0[w] = 0; c1[w] = 0; c2[w] = 0; c3[w] = 0; }

    if (mi) {
        u64 reach[NW] = {};
        u64 frontier[NW] = {};
        reach[i >> 6] = 1ULL << (i & 63);
        #pragma unroll
        for (int w = 0; w < NW; ++w) frontier[w] = reach[w];
        bool active = true;
        for (int k = 0; k <= MAXD; ++k) {
            // c += ~reach  (bit-sliced increment, 4-bit, max value 11)
            #pragma unroll
            for (int w = 0; w < NW; ++w) {
                u64 u = ~reach[w];
                u64 t0 = c0[w] & u; c0[w] ^= u;
                u64 t1 = c1[w] & t0; c1[w] ^= t0;
                u64 t2 = c2[w] & t1; c2[w] ^= t1;
                c3[w] ^= t2;
            }
            if (k == MAXD) break;
            if (active) {
                u64 acc[NW] = {};
                bool sat = false;
                for (int w = 0; w < NW && !sat; ++w) {
                    u64 f = frontier[w];
                    while (f) {
                        int j = (w << 6) + __builtin_ctzll(f);
                        f &= f - 1;
                        #pragma unroll
                        for (int e = 0; e < NW; ++e) acc[e] |= adjT[e * N + j];
                        u64 all = acc[0];
                        #pragma unroll
                        for (int e = 1; e < NW; ++e) all &= acc[e];
                        if (all == ~0ULL) { sat = true; break; }  // union saturated: exact
                    }
                }
                bool any = false;
                #pragma unroll
                for (int w = 0; w < NW; ++w) {
                    u64 nf = acc[w] & ~reach[w];
                    frontier[w] = nf;
                    reach[w] |= nf;
                    any = any || (nf != 0);
                }
                active = any;
            }
        }
    } else {
        // invalid source row: all distances = 11 = 0b1011
        #pragma unroll
        for (int w = 0; w < NW; ++w) { c0[w] = ~0ULL; c1[w] = ~0ULL; c3[w] = ~0ULL; }
    }

    // expand bit-sliced counters -> dist bytes (8 bytes per u64), stage in LDS
    #pragma unroll
    for (int w = 0; w < NW; ++w) {
        #pragma unroll
        for (int h = 0; h < 8; ++h) {
            unsigned b0 = (unsigned)(c0[w] >> (8 * h)) & 0xFF;
            unsigned b1 = (unsigned)(c1[w] >> (8 * h)) & 0xFF;
            unsigned b2 = (unsigned)(c2[w] >> (8 * h)) & 0xFF;
            unsigned b3 = (unsigned)(c3[w] >> (8 * h)) & 0xFF;
            u64 bytes = spread8(b0) | (spread8(b1) << 1) | (spread8(b2) << 2) | (spread8(b3) << 3);
            outB[t * 65 + w * 8 + h] = bytes;
        }
    }
    __syncthreads();
    // coalesced copy-out: row-major dist bytes, 64 u64 per row
    u64* dg = distg64 + (size_t)blk * 64 * 64;
    for (int q = t; q < 64 * 64; q += 64)
        dg[q] = outB[(q >> 6) * 65 + (q & 63)];
}

// ---------------- K3: dist -> emb[dist], the 268 MB streaming write ----------------
// grid: B*N blocks (one per output row), 256 threads, 4 coalesced nontemporal vf4 stores.
__global__ __launch_bounds__(256) void k3_expand(const unsigned char* __restrict__ distg,
                                                 const float* __restrict__ emb,
                                                 vf4* __restrict__ out4) {
    __shared__ unsigned char drow[N];
    __shared__ vf4 e4[(MAXD + 2) * 2];
    int row = blockIdx.x;
    int t = threadIdx.x;
    if (t < N / 4)
        ((uint32_t*)drow)[t] = ((const uint32_t*)distg)[(size_t)row * (N / 4) + t];
    if (t >= 128 && t < 128 + (MAXD + 2) * 2)
        e4[t - 128] = ((const vf4*)emb)[t - 128];
    __syncthreads();
    size_t base = (size_t)row * (N * 2);
    #pragma unroll
    for (int s = 0; s < 4; ++s) {
        int q = t + 256 * s;      // 0..1023 float4 slots in this row
        int j = q >> 1, h = q & 1;
        int d = drow[j];
        __builtin_nontemporal_store(e4[d * 2 + h], &out4[base + q]);
    }
}

extern "C" void kernel_launch(void* const* d_in, const int* in_sizes, int n_in,
                              void* d_out, int out_size, void* d_ws, size_t ws_size,
                              hipStream_t stream) {
    const float* adj = (const float*)d_in[0];
    const int* mask = (const int*)d_in[1];  // jnp bool -> int32 per harness convention
    const float* emb = (const float*)d_in[2];
    u64* gsym = (u64*)d_ws;                                             // 1 MB
    unsigned char* distg = (unsigned char*)d_ws + (size_t)NB * N * NW * 8;  // 8 MB
    k1_pack<<<dim3(36, NB), 256, 0, stream>>>(adj, mask, gsym);
    k2_bfs<<<dim3(NB * 8), 64, 0, stream>>>(gsym, mask, (u64*)distg);
    k3_expand<<<dim3(NB * N), 256, 0, stream>>>(distg, emb, (vf4*)d_out);
}

// Round 5
// 352.770 us; speedup vs baseline: 1.1148x; 1.0312x over previous
//
#include <hip/hip_runtime.h>
#include <stdint.h>

typedef unsigned long long u64;
typedef float vf4 __attribute__((ext_vector_type(4)));  // native vector: nontemporal-store OK

#define NB 32
#define N 512
#define MAXD 10
#define NW 8  // u64 words per 512-bit row

// ---------------- K1: binarize + symmetrize + mask -> packed bitset ----------------
// grid: (36 tile-pairs, B), block 256. Tiles 64x64; __ballot builds one u64 word per row.
// NOTE: node_mask arrives as int32 (harness converts jnp bool -> int).
__global__ __launch_bounds__(256) void k1_pack(const float* __restrict__ adj,
                                               const int* __restrict__ mask,
                                               u64* __restrict__ gsym) {
    __shared__ float ldsA[64 * 65];  // +1 pad: row & column reads both conflict-free
    __shared__ float ldsB[64 * 65];
    __shared__ unsigned char mI[64], mJ[64];
    int p = blockIdx.x;
    int b = blockIdx.y;
    int ti = 0;
    while (p >= 8 - ti) { p -= 8 - ti; ++ti; }
    int tj = ti + p;
    int i0 = ti * 64, j0 = tj * 64;
    int t = threadIdx.x;
    if (t < 64) mI[t] = (mask[b * N + i0 + t] != 0);
    else if (t < 128) mJ[t - 64] = (mask[b * N + j0 + (t - 64)] != 0);
    const float* Ab = adj + (size_t)b * N * N;
    #pragma unroll
    for (int s = 0; s < 4; ++s) {
        int idx = t + 256 * s;          // 0..1023 float4 slots
        int r = idx >> 4, c4 = idx & 15;
        float4 va = *(const float4*)&Ab[(size_t)(i0 + r) * N + j0 + c4 * 4];
        float4 vb = *(const float4*)&Ab[(size_t)(j0 + r) * N + i0 + c4 * 4];
        int o = r * 65 + c4 * 4;
        ldsA[o] = va.x; ldsA[o + 1] = va.y; ldsA[o + 2] = va.z; ldsA[o + 3] = va.w;
        ldsB[o] = vb.x; ldsB[o + 1] = vb.y; ldsB[o + 2] = vb.z; ldsB[o + 3] = vb.w;
    }
    __syncthreads();
    int wave = t >> 6, lane = t & 63;
    // rows of tile ti, word tj
    for (int s = 0; s < 16; ++s) {
        int r = wave * 16 + s;
        bool bit = ((ldsA[r * 65 + lane] > 0.5f) || (ldsB[lane * 65 + r] > 0.5f))
                   && mI[r] && mJ[lane];
        u64 word = __ballot(bit);
        if (lane == 0) gsym[((size_t)b * N + i0 + r) * NW + tj] = word;
    }
    // rows of tile tj, word ti (diagonal tiles: benign identical double write)
    for (int s = 0; s < 16; ++s) {
        int r = wave * 16 + s;
        bool bit = ((ldsB[r * 65 + lane] > 0.5f) || (ldsA[lane * 65 + r] > 0.5f))
                   && mJ[r] && mI[lane];
        u64 word = __ballot(bit);
        if (lane == 0) gsym[((size_t)b * N + j0 + r) * NW + ti] = word;
    }
}

// spread 8 bits -> u64 of 8 bytes each 0/1
__device__ __forceinline__ u64 spread8(unsigned b) {
    u64 x = (u64)(b * 0x01010101u);
    x |= x << 32;                       // broadcast byte to all 8 byte lanes
    x &= 0x8040201008040201ULL;         // byte i keeps bit i
    x += 0x7f7f7f7f7f7f7f7fULL;         // bit7 of byte i = (bit i was set); no cross-byte carry
    return (x >> 7) & 0x0101010101010101ULL;
}

// ---------------- K23: fused bitset-BFS + embedding expansion ----------------
// grid: B*8 blocks, 256 threads (4 waves). Wave 0 runs 64 per-source-row BFS with
// bit-sliced 4-bit distance counters; dist bytes staged in LDS; then ALL 4 waves
// stream the 1 MB output slab (64 rows x 512 x 8 fp32) with nontemporal stores.
// Kills the distg HBM roundtrip + third kernel launch of the previous version.
__global__ __launch_bounds__(256) void k23_bfs_expand(const u64* __restrict__ gsym,
                                                      const int* __restrict__ mask,
                                                      const float* __restrict__ emb,
                                                      vf4* __restrict__ out4) {
    __shared__ u64 adjT[NW * N];      // 32 KB, plane-major [w][j]: 4-way aliasing only
    __shared__ u64 outB[64 * 65];     // packed dist bytes, pad 65 breaks stride-128
    __shared__ vf4 e4[(MAXD + 2) * 2];
    int blk = blockIdx.x;
    int b = blk >> 3;
    int r0 = (blk & 7) * 64;
    int t = threadIdx.x;
    const u64* gs = gsym + (size_t)b * N * NW;
    for (int q = t; q < N * NW; q += 256) {
        u64 w = gs[q];                           // coalesced global read
        adjT[(q & 7) * N + (q >> 3)] = w;        // transpose to plane-major
    }
    if (t >= 64 && t < 64 + (MAXD + 2) * 2)
        e4[t - 64] = ((const vf4*)emb)[t - 64];
    __syncthreads();

    if (t < 64) {
        int i = r0 + t;
        bool mi = mask[b * N + i] != 0;
        u64 c0[NW], c1[NW], c2[NW], c3[NW];
        #pragma unroll
        for (int w = 0; w < NW; ++w) { c0[w] = 0; c1[w] = 0; c2[w] = 0; c3[w] = 0; }

        if (mi) {
            u64 reach[NW] = {};
            u64 frontier[NW] = {};
            reach[i >> 6] = 1ULL << (i & 63);
            #pragma unroll
            for (int w = 0; w < NW; ++w) frontier[w] = reach[w];
            bool active = true;
            for (int k = 0; k <= MAXD; ++k) {
                // c += ~reach  (bit-sliced increment, 4-bit, max value 11)
                #pragma unroll
                for (int w = 0; w < NW; ++w) {
                    u64 u = ~reach[w];
                    u64 t0 = c0[w] & u; c0[w] ^= u;
                    u64 t1 = c1[w] & t0; c1[w] ^= t0;
                    u64 t2 = c2[w] & t1; c2[w] ^= t1;
                    c3[w] ^= t2;
                }
                if (k == MAXD) break;
                if (active) {
                    u64 acc[NW] = {};
                    bool sat = false;
                    for (int w = 0; w < NW && !sat; ++w) {
                        u64 f = frontier[w];
                        while (f) {
                            int j = (w << 6) + __builtin_ctzll(f);
                            f &= f - 1;
                            #pragma unroll
                            for (int e = 0; e < NW; ++e) acc[e] |= adjT[e * N + j];
                            u64 all = acc[0];
                            #pragma unroll
                            for (int e = 1; e < NW; ++e) all &= acc[e];
                            if (all == ~0ULL) { sat = true; break; }  // union saturated: exact
                        }
                    }
                    bool any = false;
                    #pragma unroll
                    for (int w = 0; w < NW; ++w) {
                        u64 nf = acc[w] & ~reach[w];
                        frontier[w] = nf;
                        reach[w] |= nf;
                        any = any || (nf != 0);
                    }
                    active = any;
                }
            }
        } else {
            // invalid source row: all distances = 11 = 0b1011
            #pragma unroll
            for (int w = 0; w < NW; ++w) { c0[w] = ~0ULL; c1[w] = ~0ULL; c3[w] = ~0ULL; }
        }

        // expand bit-sliced counters -> dist bytes (8 per u64) into LDS
        #pragma unroll
        for (int w = 0; w < NW; ++w) {
            #pragma unroll
            for (int h = 0; h < 8; ++h) {
                unsigned b0 = (unsigned)(c0[w] >> (8 * h)) & 0xFF;
                unsigned b1 = (unsigned)(c1[w] >> (8 * h)) & 0xFF;
                unsigned b2 = (unsigned)(c2[w] >> (8 * h)) & 0xFF;
                unsigned b3 = (unsigned)(c3[w] >> (8 * h)) & 0xFF;
                outB[t * 65 + w * 8 + h] =
                    spread8(b0) | (spread8(b1) << 1) | (spread8(b2) << 2) | (spread8(b3) << 3);
            }
        }
    }
    __syncthreads();

    // expansion: 64 rows x 1024 vf4 slots, all 256 threads, nontemporal streaming stores
    const unsigned char* db = (const unsigned char*)outB;
    vf4* outp = out4 + ((size_t)(b * N + r0)) * (N * 2);
    for (int r = 0; r < 64; ++r) {
        const unsigned char* drow = db + r * 65 * 8;
        vf4* rowp = outp + (size_t)r * (N * 2);
        #pragma unroll
        for (int s = 0; s < 4; ++s) {
            int q = t + 256 * s;      // 0..1023 vf4 slots in this row
            int j = q >> 1, h = q & 1;
            int d = drow[j];
            __builtin_nontemporal_store(e4[d * 2 + h], &rowp[q]);
        }
    }
}

extern "C" void kernel_launch(void* const* d_in, const int* in_sizes, int n_in,
                              void* d_out, int out_size, void* d_ws, size_t ws_size,
                              hipStream_t stream) {
    const float* adj = (const float*)d_in[0];
    const int* mask = (const int*)d_in[1];  // jnp bool -> int32 per harness convention
    const float* emb = (const float*)d_in[2];
    u64* gsym = (u64*)d_ws;                 // 1 MB scratch
    k1_pack<<<dim3(36, NB), 256, 0, stream>>>(adj, mask, gsym);
    k23_bfs_expand<<<dim3(NB * 8), 256, 0, stream>>>(gsym, mask, emb, (vf4*)d_out);
}

// Round 6
// 351.359 us; speedup vs baseline: 1.1192x; 1.0040x over previous
//
#include <hip/hip_runtime.h>
#include <stdint.h>

typedef unsigned long long u64;
typedef float vf4 __attribute__((ext_vector_type(4)));

#define NB 32
#define N 512
#define MAXD 10
#define NW 8  // u64 words per 512-bit row

// ---------------- K1: binarize + symmetrize + mask -> packed bitset ----------------
// grid: (36 tile-pairs, B), block 256. Tiles 64x64; __ballot builds one u64 word per row.
// NOTE: node_mask arrives as int32 (harness converts jnp bool -> int).
__global__ __launch_bounds__(256) void k1_pack(const float* __restrict__ adj,
                                               const int* __restrict__ mask,
                                               u64* __restrict__ gsym) {
    __shared__ float ldsA[64 * 65];  // +1 pad: row & column reads both conflict-free
    __shared__ float ldsB[64 * 65];
    __shared__ unsigned char mI[64], mJ[64];
    int p = blockIdx.x;
    int b = blockIdx.y;
    int ti = 0;
    while (p >= 8 - ti) { p -= 8 - ti; ++ti; }
    int tj = ti + p;
    int i0 = ti * 64, j0 = tj * 64;
    int t = threadIdx.x;
    if (t < 64) mI[t] = (mask[b * N + i0 + t] != 0);
    else if (t < 128) mJ[t - 64] = (mask[b * N + j0 + (t - 64)] != 0);
    const float* Ab = adj + (size_t)b * N * N;
    #pragma unroll
    for (int s = 0; s < 4; ++s) {
        int idx = t + 256 * s;          // 0..1023 float4 slots
        int r = idx >> 4, c4 = idx & 15;
        float4 va = *(const float4*)&Ab[(size_t)(i0 + r) * N + j0 + c4 * 4];
        float4 vb = *(const float4*)&Ab[(size_t)(j0 + r) * N + i0 + c4 * 4];
        int o = r * 65 + c4 * 4;
        ldsA[o] = va.x; ldsA[o + 1] = va.y; ldsA[o + 2] = va.z; ldsA[o + 3] = va.w;
        ldsB[o] = vb.x; ldsB[o + 1] = vb.y; ldsB[o + 2] = vb.z; ldsB[o + 3] = vb.w;
    }
    __syncthreads();
    int wave = t >> 6, lane = t & 63;
    // rows of tile ti, word tj
    for (int s = 0; s < 16; ++s) {
        int r = wave * 16 + s;
        bool bit = ((ldsA[r * 65 + lane] > 0.5f) || (ldsB[lane * 65 + r] > 0.5f))
                   && mI[r] && mJ[lane];
        u64 word = __ballot(bit);
        if (lane == 0) gsym[((size_t)b * N + i0 + r) * NW + tj] = word;
    }
    // rows of tile tj, word ti (diagonal tiles: benign identical double write)
    for (int s = 0; s < 16; ++s) {
        int r = wave * 16 + s;
        bool bit = ((ldsB[r * 65 + lane] > 0.5f) || (ldsA[lane * 65 + r] > 0.5f))
                   && mJ[r] && mI[lane];
        u64 word = __ballot(bit);
        if (lane == 0) gsym[((size_t)b * N + j0 + r) * NW + ti] = word;
    }
}

// spread 8 bits -> u64 of 8 bytes each 0/1
__device__ __forceinline__ u64 spread8(unsigned b) {
    u64 x = (u64)(b * 0x01010101u);
    x |= x << 32;                       // broadcast byte to all 8 byte lanes
    x &= 0x8040201008040201ULL;         // byte i keeps bit i
    x += 0x7f7f7f7f7f7f7f7fULL;         // bit7 of byte i = (bit i was set); no cross-byte carry
    return (x >> 7) & 0x0101010101010101ULL;
}

// ---------------- K23: fused bitset-BFS + embedding expansion ----------------
// grid: B*8 blocks, 256 threads (4 waves). Wave 0 runs 64 per-source-row BFS with
// bit-sliced 4-bit distance counters; dist bytes staged in LDS; then ALL 4 waves
// stream the 1 MB output slab. A/B vs round 5: PLAIN stores (no nontemporal) —
// fills prove plain write path sustains ~6.4 TB/s; nt may bypass write-combining.
__global__ __launch_bounds__(256) void k23_bfs_expand(const u64* __restrict__ gsym,
                                                      const int* __restrict__ mask,
                                                      const float* __restrict__ emb,
                                                      vf4* __restrict__ out4) {
    __shared__ u64 adjT[NW * N];      // 32 KB, plane-major [w][j]: 4-way aliasing only
    __shared__ u64 outB[64 * 65];     // packed dist bytes, pad 65 breaks stride-128
    __shared__ vf4 e4[(MAXD + 2) * 2];
    int blk = blockIdx.x;
    int b = blk >> 3;
    int r0 = (blk & 7) * 64;
    int t = threadIdx.x;
    const u64* gs = gsym + (size_t)b * N * NW;
    for (int q = t; q < N * NW; q += 256) {
        u64 w = gs[q];                           // coalesced global read
        adjT[(q & 7) * N + (q >> 3)] = w;        // transpose to plane-major
    }
    if (t >= 64 && t < 64 + (MAXD + 2) * 2)
        e4[t - 64] = ((const vf4*)emb)[t - 64];
    __syncthreads();

    if (t < 64) {
        int i = r0 + t;
        bool mi = mask[b * N + i] != 0;
        u64 c0[NW], c1[NW], c2[NW], c3[NW];
        #pragma unroll
        for (int w = 0; w < NW; ++w) { c0[w] = 0; c1[w] = 0; c2[w] = 0; c3[w] = 0; }

        if (mi) {
            u64 reach[NW] = {};
            u64 frontier[NW] = {};
            reach[i >> 6] = 1ULL << (i & 63);
            #pragma unroll
            for (int w = 0; w < NW; ++w) frontier[w] = reach[w];
            bool active = true;
            for (int k = 0; k <= MAXD; ++k) {
                // c += ~reach  (bit-sliced increment, 4-bit, max value 11)
                #pragma unroll
                for (int w = 0; w < NW; ++w) {
                    u64 u = ~reach[w];
                    u64 t0 = c0[w] & u; c0[w] ^= u;
                    u64 t1 = c1[w] & t0; c1[w] ^= t0;
                    u64 t2 = c2[w] & t1; c2[w] ^= t1;
                    c3[w] ^= t2;
                }
                if (k == MAXD) break;
                if (active) {
                    u64 acc[NW] = {};
                    bool sat = false;
                    for (int w = 0; w < NW && !sat; ++w) {
                        u64 f = frontier[w];
                        while (f) {
                            int j = (w << 6) + __builtin_ctzll(f);
                            f &= f - 1;
                            #pragma unroll
                            for (int e = 0; e < NW; ++e) acc[e] |= adjT[e * N + j];
                            u64 all = acc[0];
                            #pragma unroll
                            for (int e = 1; e < NW; ++e) all &= acc[e];
                            if (all == ~0ULL) { sat = true; break; }  // union saturated: exact
                        }
                    }
                    bool any = false;
                    #pragma unroll
                    for (int w = 0; w < NW; ++w) {
                        u64 nf = acc[w] & ~reach[w];
                        frontier[w] = nf;
                        reach[w] |= nf;
                        any = any || (nf != 0);
                    }
                    active = any;
                }
            }
        } else {
            // invalid source row: all distances = 11 = 0b1011
            #pragma unroll
            for (int w = 0; w < NW; ++w) { c0[w] = ~0ULL; c1[w] = ~0ULL; c3[w] = ~0ULL; }
        }

        // expand bit-sliced counters -> dist bytes (8 per u64) into LDS
        #pragma unroll
        for (int w = 0; w < NW; ++w) {
            #pragma unroll
            for (int h = 0; h < 8; ++h) {
                unsigned b0 = (unsigned)(c0[w] >> (8 * h)) & 0xFF;
                unsigned b1 = (unsigned)(c1[w] >> (8 * h)) & 0xFF;
                unsigned b2 = (unsigned)(c2[w] >> (8 * h)) & 0xFF;
                unsigned b3 = (unsigned)(c3[w] >> (8 * h)) & 0xFF;
                outB[t * 65 + w * 8 + h] =
                    spread8(b0) | (spread8(b1) << 1) | (spread8(b2) << 2) | (spread8(b3) << 3);
            }
        }
    }
    __syncthreads();

    // expansion: 64 rows x 1024 vf4 slots, all 256 threads, plain coalesced stores
    const unsigned char* db = (const unsigned char*)outB;
    vf4* outp = out4 + ((size_t)(b * N + r0)) * (N * 2);
    for (int r = 0; r < 64; ++r) {
        const unsigned char* drow = db + r * 65 * 8;
        vf4* rowp = outp + (size_t)r * (N * 2);
        #pragma unroll
        for (int s = 0; s < 4; ++s) {
            int q = t + 256 * s;      // 0..1023 vf4 slots in this row
            int j = q >> 1, h = q & 1;
            int d = drow[j];
            rowp[q] = e4[d * 2 + h];
        }
    }
}

extern "C" void kernel_launch(void* const* d_in, const int* in_sizes, int n_in,
                              void* d_out, int out_size, void* d_ws, size_t ws_size,
                              hipStream_t stream) {
    const float* adj = (const float*)d_in[0];
    const int* mask = (const int*)d_in[1];  // jnp bool -> int32 per harness convention
    const float* emb = (const float*)d_in[2];
    u64* gsym = (u64*)d_ws;                 // 1 MB scratch
    k1_pack<<<dim3(36, NB), 256, 0, stream>>>(adj, mask, gsym);
    k23_bfs_expand<<<dim3(NB * 8), 256, 0, stream>>>(gsym, mask, emb, (vf4*)d_out);
}